// Round 4
// baseline (639.858 us; speedup 1.0000x reference)
//
#include <hip/hip_runtime.h>

// T2ICrossAttentionPool on MI355X.
// Identities: w12[c,i,w] = sum_r attn*Sraw;  |wctx|^2 = a^T G a with
//   G = exact fp32 diag (register math) + off-diag G' bf16 (MFMA quadratic form).
// R11: k_gram -> MFMA; XCD swizzle. R12: depth-3 reg pipeline. R13: transposed
//   epilogue (MfmaUtil 27%, calibrated MFMA floor = 124us = 27% of 433us).
// R14: K-loop was TA-bandwidth-bound (11.5 GB fragment loads = 43 B/cy/CU of
//   ~64 peak; every fragment fetched 2x per block). Cooperative LDS staging:
//   per k32 each fragment staged ONCE via global_load_lds (wave roles), double
//   buffered, 1 __syncthreads/k32; waves ds_read_b128 from LDS (separate pipe).
//   TA floor 147us/CU, MFMA floor 124us. + caption length-sort so block's two
//   caps have equal mlim (barrier balance). launch_bounds(256,4), LDS 35840
//   (stage union'd with attn region) -> 4 blocks/CU, 50% occupancy.

#define NIMG 256
#define NREG 36
#define DIM 1024
#define NCAP 256
#define MAXW 60
#define WPAD 64

typedef short bf16x8 __attribute__((ext_vector_type(8)));
typedef float f32x4 __attribute__((ext_vector_type(4)));

__device__ __forceinline__ unsigned short f2bf(float f) {
  unsigned u = __float_as_uint(f);
  u += 0x7FFF + ((u >> 16) & 1);   // round-to-nearest-even
  return (unsigned short)(u >> 16);
}

// async global->LDS, 16B per lane; LDS dest = uniform base + lane*16
__device__ __forceinline__ void gll16(const unsigned short* g, unsigned short* l) {
  __builtin_amdgcn_global_load_lds((const __attribute__((address_space(1))) void*)g,
                                   (__attribute__((address_space(3))) void*)l, 16, 0, 0);
}

// ---- prep: w1[c][w] = ||masked q row|| ----
__global__ void k_prep_w1(const float* __restrict__ caps, const int* __restrict__ cap_lens,
                          float* __restrict__ w1) {
  const int bid = blockIdx.x;          // c*64 + w
  const int c = bid >> 6;
  const int w = bid & 63;
  const int t = threadIdx.x;
  const bool valid = (w < MAXW) && (w < cap_lens[c]);
  float4 v = make_float4(0.f, 0.f, 0.f, 0.f);
  if (valid) v = *reinterpret_cast<const float4*>(caps + ((size_t)c * MAXW + w) * DIM + t * 4);
  float ss = v.x * v.x + v.y * v.y + v.z * v.z + v.w * v.w;
#pragma unroll
  for (int m = 1; m <= 32; m <<= 1) ss += __shfl_xor(ss, m);
  __shared__ float part[4];
  if ((t & 63) == 0) part[t >> 6] = ss;
  __syncthreads();
  if (t == 0) w1[bid] = sqrtf(part[0] + part[1] + part[2] + part[3]);
}

// ---- prep: caption permutation sorted by length (rank-count, 1 block) ----
__global__ void k_sort(const int* __restrict__ cap_lens, int* __restrict__ perm) {
  const int i = threadIdx.x;           // 256 threads
  const int li = cap_lens[i];
  int r = 0;
  for (int j = 0; j < NCAP; ++j) {
    const int lj = cap_lens[j];
    r += (lj < li) || (lj == li && j < i);
  }
  perm[r] = i;
}

// ---- prep: caps -> fragments, masked (rows w>=clen zero) ----
// Layout: qbfF[(((c*32 + k32)*4 + mt)*64 + lane)*8 + j]
//   = q[c][m = mt*16 + (lane&15)][k = k32*32 + (lane>>4)*8 + j]
__global__ void k_prep_caps_frag(const float* __restrict__ caps, const int* __restrict__ cap_lens,
                                 unsigned short* __restrict__ qbfF) {
  const int k32 = blockIdx.x;
  const int c = blockIdx.y;
  const int t = threadIdx.x;
  const int mt = t >> 6;
  const int lane = t & 63;
  const int m = mt * 16 + (lane & 15);
  const int k0 = k32 * 32 + (lane >> 4) * 8;
  const int clen = cap_lens[c];
  float4 v0 = make_float4(0.f, 0.f, 0.f, 0.f), v1 = v0;
  if (m < clen && m < MAXW) {
    const float* src = caps + ((size_t)c * MAXW + m) * DIM + k0;
    v0 = *reinterpret_cast<const float4*>(src);
    v1 = *reinterpret_cast<const float4*>(src + 4);
  }
  ushort4 o0, o1;
  o0.x = f2bf(v0.x); o0.y = f2bf(v0.y); o0.z = f2bf(v0.z); o0.w = f2bf(v0.w);
  o1.x = f2bf(v1.x); o1.y = f2bf(v1.y); o1.z = f2bf(v1.z); o1.w = f2bf(v1.w);
  unsigned short* dst = qbfF + ((size_t)(((c * 32 + k32) * 4 + mt) * 64 + lane)) * 8;
  *reinterpret_cast<ushort4*>(dst) = o0;
  *reinterpret_cast<ushort4*>(dst + 4) = o1;
}

// ---- prep: imgs -> fragments (rows r>=36 zero) ----
// Layout: ibfF[(((i*32 + k32)*3 + nt)*64 + lane)*8 + j]
//   = imgs[i][r = nt*16 + (lane&15)][k = k32*32 + (lane>>4)*8 + j]
__global__ void k_prep_imgs_frag(const float* __restrict__ imgs,
                                 unsigned short* __restrict__ ibfF) {
  const int k32 = blockIdx.x;
  const int i = blockIdx.y;
  const int t = threadIdx.x;          // 0..191
  const int nt = t >> 6;
  const int lane = t & 63;
  const int r = nt * 16 + (lane & 15);
  const int k0 = k32 * 32 + (lane >> 4) * 8;
  float4 v0 = make_float4(0.f, 0.f, 0.f, 0.f), v1 = v0;
  if (r < NREG) {
    const float* src = imgs + ((size_t)i * NREG + r) * DIM + k0;
    v0 = *reinterpret_cast<const float4*>(src);
    v1 = *reinterpret_cast<const float4*>(src + 4);
  }
  ushort4 o0, o1;
  o0.x = f2bf(v0.x); o0.y = f2bf(v0.y); o0.z = f2bf(v0.z); o0.w = f2bf(v0.w);
  o1.x = f2bf(v1.x); o1.y = f2bf(v1.y); o1.z = f2bf(v1.z); o1.w = f2bf(v1.w);
  unsigned short* dst = ibfF + ((size_t)(((i * 32 + k32) * 3 + nt) * 64 + lane)) * 8;
  *reinterpret_cast<ushort4*>(dst) = o0;
  *reinterpret_cast<ushort4*>(dst + 4) = o1;
}

// ---- Gram via MFMA: one wave per image (same ibfF line feeds both operands) ----
__global__ void k_gram_mfma(const float* __restrict__ imgs,
                            const unsigned short* __restrict__ ibfF,
                            unsigned short* __restrict__ gbf,
                            float* __restrict__ gdiag) {
  const int i = blockIdx.x;
  const int lane = threadIdx.x & 63;
  const int l15 = lane & 15;
  const int quad = lane >> 4;

  // exact fp32 diag: rows r0+quad, k split across the 16 lanes of each quad
  float* dg = gdiag + (size_t)i * 48;
#pragma unroll
  for (int r0 = 0; r0 < 36; r0 += 4) {
    const int r = r0 + quad;
    const float* row = imgs + ((size_t)i * NREG + r) * DIM;
    float ss = 0.f;
#pragma unroll
    for (int p = 0; p < 16; ++p) {
      float4 v = *reinterpret_cast<const float4*>(row + p * 64 + l15 * 4);
      ss += v.x * v.x + v.y * v.y + v.z * v.z + v.w * v.w;
    }
    ss += __shfl_xor(ss, 1); ss += __shfl_xor(ss, 2);
    ss += __shfl_xor(ss, 4); ss += __shfl_xor(ss, 8);
    if (l15 == 0) dg[r] = ss;
  }
  if (lane < 12) dg[36 + lane] = 0.f;

  const unsigned short* base = ibfF + ((size_t)i * 32 * 3) * 512 + lane * 8;
  const f32x4 zero4 = {0.f, 0.f, 0.f, 0.f};
  f32x4 acc[3][3];
#pragma unroll
  for (int na = 0; na < 3; ++na)
#pragma unroll
    for (int nb = 0; nb < 3; ++nb) acc[na][nb] = zero4;
  bf16x8 f[2][3];
#pragma unroll
  for (int nt = 0; nt < 3; ++nt)
    f[0][nt] = *reinterpret_cast<const bf16x8*>(base + (size_t)nt * 512);
#pragma unroll
  for (int k32 = 0; k32 < 32; ++k32) {
    if (k32 + 1 < 32) {
      const int nb_ = (k32 + 1) & 1;
#pragma unroll
      for (int nt = 0; nt < 3; ++nt)
        f[nb_][nt] = *reinterpret_cast<const bf16x8*>(base + ((size_t)(k32 + 1) * 3 + nt) * 512);
    }
    const int b = k32 & 1;
#pragma unroll
    for (int na = 0; na < 3; ++na)
#pragma unroll
      for (int nb = 0; nb < 3; ++nb)
        acc[na][nb] = __builtin_amdgcn_mfma_f32_16x16x32_bf16(f[b][na], f[b][nb], acc[na][nb], 0, 0, 0);
  }
  unsigned short* g = gbf + (size_t)i * (48 * 64);
#pragma unroll
  for (int na = 0; na < 3; ++na)
#pragma unroll
    for (int nb = 0; nb < 3; ++nb)
#pragma unroll
      for (int rg = 0; rg < 4; ++rg) {
        const int r = na * 16 + quad * 4 + rg;   // C row
        const int c = nb * 16 + l15;             // C col
        g[r * 64 + c] = (r == c) ? (unsigned short)0 : f2bf(acc[na][nb][rg]);
      }
  // zero the K-pad cols 48..63 (16 ushorts = 2 uint4 per row)
  for (int idx = lane; idx < 96; idx += 64) {
    const int r = idx >> 1, half = idx & 1;
    *reinterpret_cast<uint4*>(g + r * 64 + 48 + half * 8) = make_uint4(0, 0, 0, 0);
  }
}

// ---- K-loop: LDS-staged, double-buffered, 1 barrier per k32 ----
// Stage: this wave issues sCnt global_load_lds (its role's fragments) for the
// NEXT k32 into buf^1, then ds_reads its own operands from buf, MFMAs, and
// __syncthreads() (drains vmcnt -> next buf staged by all waves).
#define BUFO 7168   // ushorts per stage buffer
template <int MLIM>
__device__ __forceinline__ void kloopS(const unsigned short* __restrict__ sSrc,
                                       unsigned short* __restrict__ sDst,
                                       const int sCnt, const size_t sK32,
                                       const unsigned short* __restrict__ aLds,
                                       const unsigned short* __restrict__ bLds,
                                       f32x4 (&acc)[3][4]) {
  // prologue: stage k32=0 into buf 0
  for (int j = 0; j < sCnt; ++j)
    gll16(sSrc + j * 512, sDst + j * 512);
  __syncthreads();
#pragma unroll 2
  for (int t = 0; t < 32; ++t) {
    const int cur = t & 1;
    if (t + 1 < 32) {
      unsigned short* d = sDst + (cur ^ 1) * BUFO;
      const unsigned short* s = sSrc + (size_t)(t + 1) * sK32;
      for (int j = 0; j < sCnt; ++j)
        gll16(s + j * 512, d + j * 512);
    }
    bf16x8 fb[3], fa[MLIM];
#pragma unroll
    for (int nt = 0; nt < 3; ++nt)
      fb[nt] = *reinterpret_cast<const bf16x8*>(bLds + cur * BUFO + nt * 512);
#pragma unroll
    for (int mt = 0; mt < MLIM; ++mt)
      fa[mt] = *reinterpret_cast<const bf16x8*>(aLds + cur * BUFO + mt * 512);
#pragma unroll
    for (int mt = 0; mt < MLIM; ++mt)
#pragma unroll
      for (int nt = 0; nt < 3; ++nt)
        acc[nt][mt] = __builtin_amdgcn_mfma_f32_16x16x32_bf16(fb[nt], fa[mt], acc[nt][mt], 0, 0, 0);
    __syncthreads();
  }
}

// ---- main fused kernel ----
// Grid (I/2, C/2), block 256 = 4 waves: wave wv -> (cap wv&1 of sorted pair,
// img i0+(wv>>1)). XCD swizzle: each XCD owns a 16-wide image-pair stripe.
__launch_bounds__(256, 4)
__global__ void k_main(const unsigned short* __restrict__ qbfF,
                       const unsigned short* __restrict__ ibfF,
                       const float* __restrict__ w1,
                       const unsigned short* __restrict__ gbf,
                       const float* __restrict__ gdiag,
                       const int* __restrict__ cap_lens,
                       const int* __restrict__ perm,
                       float* __restrict__ out) {
  __shared__ union {
    unsigned short stg[2][BUFO];      // [dbuf][capA 4t | capB 4t | img0 3t | img1 3t] = 28672 B
    unsigned short attn[4][4096];     // post-loop: bf16 [w][r] per wave, 32768 B
  } u;
  __shared__ float w12s[4][64], w2ds[4][64], w2xs[4][64];   // 3072 B -> total 35840
  const int tid = threadIdx.x;
  const int lane = tid & 63;
  const int wv = tid >> 6;
  const int l15 = lane & 15;
  const int quad = lane >> 4;
  // ---- XCD-aware swizzle (16384 blocks, %8==0 -> bijective) ----
  const int flat = blockIdx.y * (NIMG / 2) + blockIdx.x;
  const int xcd = flat & 7;
  const int idx = flat >> 3;
  const int bx = xcd * 16 + (idx & 15);
  const int by = idx >> 4;
  const int i0 = bx * 2;
  const int cA = perm[2 * by], cB = perm[2 * by + 1];
  const int c = (wv & 1) ? cB : cA;
  const int img = i0 + (wv >> 1);
  const int clen = cap_lens[c];
  const int mlim = (clen + 15) >> 4;   // 1..4 valid w-tiles (this wave)

  // stage role: wv0->capA frags, wv1->capB, wv2->img0, wv3->img1
  const unsigned short* sSrc;
  unsigned short* sDst;
  int sCnt;
  size_t sK32;
  if (wv == 0) {
    sSrc = qbfF + (size_t)cA * 32 * 4 * 512; sDst = &u.stg[0][0];
    sCnt = (cap_lens[cA] + 15) >> 4; sK32 = 4 * 512;
  } else if (wv == 1) {
    sSrc = qbfF + (size_t)cB * 32 * 4 * 512; sDst = &u.stg[0][2048];
    sCnt = (cap_lens[cB] + 15) >> 4; sK32 = 4 * 512;
  } else if (wv == 2) {
    sSrc = ibfF + (size_t)i0 * 32 * 3 * 512; sDst = &u.stg[0][4096];
    sCnt = 3; sK32 = 3 * 512;
  } else {
    sSrc = ibfF + (size_t)(i0 + 1) * 32 * 3 * 512; sDst = &u.stg[0][5632];
    sCnt = 3; sK32 = 3 * 512;
  }
  sSrc += lane * 8;
  const unsigned short* aLds = &u.stg[0][(wv & 1) * 2048] + lane * 8;
  const unsigned short* bLds = &u.stg[0][4096 + (wv >> 1) * 1536] + lane * 8;

  f32x4 acc[3][4];
  const f32x4 zero4 = {0.f, 0.f, 0.f, 0.f};
#pragma unroll
  for (int nt = 0; nt < 3; ++nt)
#pragma unroll
    for (int mt = 0; mt < 4; ++mt) acc[nt][mt] = zero4;

  switch (mlim) {
    case 1: kloopS<1>(sSrc, sDst, sCnt, sK32, aLds, bLds, acc); break;
    case 2: kloopS<2>(sSrc, sDst, sCnt, sK32, aLds, bLds, acc); break;
    case 3: kloopS<3>(sSrc, sDst, sCnt, sK32, aLds, bLds, acc); break;
    default: kloopS<4>(sSrc, sDst, sCnt, sK32, aLds, bLds, acc); break;
  }
  // last loop iteration ended with __syncthreads(): stage buffers dead, union
  // safe to reuse as attn region (wave-private slices from here on).

  {
    uint4* ab = reinterpret_cast<uint4*>(&u.attn[wv][0]);
    const uint4 z4 = make_uint4(0, 0, 0, 0);
    for (int j = lane; j < 512; j += 64) ab[j] = z4;   // zero all (incl. pad groups)
  }

  // exact diag per register row r = nt*16 + quad*4 + rg
  const float* dg = gdiag + (size_t)img * 48;
  float dv[3][4];
#pragma unroll
  for (int nt = 0; nt < 3; ++nt)
#pragma unroll
    for (int rg = 0; rg < 4; ++rg)
      dv[nt][rg] = dg[nt * 16 + quad * 4 + rg];

  // pass 1: per-region l2 norm over w -> scale (w = lane dim: in-reg over mt,
  // then xor1..8; 12 independent butterflies, ILP-overlapped)
  float scale[3][4];
#pragma unroll
  for (int nt = 0; nt < 3; ++nt)
#pragma unroll
    for (int rg = 0; rg < 4; ++rg) {
      float p = 0.f;
#pragma unroll
      for (int mt = 0; mt < 4; ++mt)
        if (mt < mlim) {
          const float s = acc[nt][mt][rg];
          const float l = s < 0.f ? 0.1f * s : s;
          p += l * l;
        }
      p += __shfl_xor(p, 1); p += __shfl_xor(p, 2);
      p += __shfl_xor(p, 4); p += __shfl_xor(p, 8);
      scale[nt][rg] = 9.0f / (sqrtf(p) + 1e-8f);   // SMOOTH folded in
    }

  // pass 2: softmax over r per w-column. |t| <= 9 (norm >= |leak| elementwise)
  // -> no max subtraction needed. Invalid r (>=36): nt==2 && quad!=0 -> e=0.
  float a_all[4][3][4];   // un-normalized e; inv folded in at use sites
  float inv4[4];
#pragma unroll
  for (int mt = 0; mt < 4; ++mt) {
    if (mt >= mlim) continue;
    float sm = 0.f, wp = 0.f, dd = 0.f;
#pragma unroll
    for (int nt = 0; nt < 3; ++nt) {
      const bool rvalid = (nt < 2) || (quad == 0);
#pragma unroll
      for (int rg = 0; rg < 4; ++rg) {
        const float s = acc[nt][mt][rg];
        const float l = s < 0.f ? 0.1f * s : s;
        const float ee = rvalid ? __expf(l * scale[nt][rg]) : 0.f;
        a_all[mt][nt][rg] = ee;
        sm += ee;
        wp += ee * s;                       // w12 uses RAW s
        dd += ee * ee * dv[nt][rg];         // exact diag term
      }
    }
    sm += __shfl_xor(sm, 16); sm += __shfl_xor(sm, 32);
    wp += __shfl_xor(wp, 16); wp += __shfl_xor(wp, 32);
    dd += __shfl_xor(dd, 16); dd += __shfl_xor(dd, 32);
    const float inv = 1.0f / sm;
    inv4[mt] = inv;
    const int w = mt * 16 + l15;
    const int key = l15 & 7;
    unsigned short* arow = &u.attn[wv][w * 64];
#pragma unroll
    for (int nt = 0; nt < 3; ++nt)
#pragma unroll
      for (int rg = 0; rg < 4; ++rg) {
        const int r = nt * 16 + quad * 4 + rg;
        arow[(((r >> 3) ^ key) << 3) + (r & 7)] = f2bf(a_all[mt][nt][rg] * inv);
      }
    if (quad == 0) { w12s[wv][w] = wp * inv; w2ds[wv][w] = dd * inv * inv; }
  }

  // Yt = G x Attn^T via MFMA (A=G rows r, B=attn cols w) -> Yt[nt][rg] at lane
  // (l15,quad) = Y[r = nt*16+quad*4+rg][w = mt*16+l15]: SAME layout as a_all.
  bf16x8 gfrag[3][2];
#pragma unroll
  for (int nt = 0; nt < 3; ++nt)
#pragma unroll
    for (int ks = 0; ks < 2; ++ks)
      gfrag[nt][ks] = *reinterpret_cast<const bf16x8*>(
          gbf + ((size_t)img * 48 + nt * 16 + l15) * 64 + ((ks * 4 + quad) << 3));
#pragma unroll
  for (int mt = 0; mt < 4; ++mt) {
    if (mt >= mlim) continue;
    bf16x8 af[2];
#pragma unroll
    for (int ks = 0; ks < 2; ++ks)
      af[ks] = *reinterpret_cast<const bf16x8*>(
          &u.attn[wv][(mt * 16 + l15) * 64 + (((ks * 4 + quad) ^ (l15 & 7)) << 3)]);
    f32x4 Yt[3] = {zero4, zero4, zero4};
#pragma unroll
    for (int nt = 0; nt < 3; ++nt)
#pragma unroll
      for (int ks = 0; ks < 2; ++ks)
        Yt[nt] = __builtin_amdgcn_mfma_f32_16x16x32_bf16(gfrag[nt][ks], af[ks], Yt[nt], 0, 0, 0);
    // cross term: w2x[w] = sum_r a[w][r] * Y[r][w] (register-local dot)
    float p = 0.f;
#pragma unroll
    for (int nt = 0; nt < 3; ++nt)
#pragma unroll
      for (int rg = 0; rg < 4; ++rg)
        p += a_all[mt][nt][rg] * Yt[nt][rg];
    p *= inv4[mt];   // a_all holds un-normalized e
    p += __shfl_xor(p, 16); p += __shfl_xor(p, 32);
    if (quad == 0) w2xs[wv][mt * 16 + l15] = p;
  }

  // final: lane = word
  float simv = 0.f;
  if (lane < clen) {
    const float w2sq = fmaxf(w2xs[wv][lane] + w2ds[wv][lane], 0.f);
    const float w2v = sqrtf(w2sq);
    const float w12v = w12s[wv][lane];
    const float w1v = w1[(size_t)c * WPAD + lane];
    simv = w12v / fmaxf(w1v * w2v, 1e-8f);
  }
  simv += __shfl_xor(simv, 1);
  simv += __shfl_xor(simv, 2);
  simv += __shfl_xor(simv, 4);
  simv += __shfl_xor(simv, 8);
  simv += __shfl_xor(simv, 16);
  simv += __shfl_xor(simv, 32);
  if (lane == 0) out[(size_t)img * NCAP + c] = simv / (float)clen;
}

extern "C" void kernel_launch(void* const* d_in, const int* in_sizes, int n_in,
                              void* d_out, int out_size, void* d_ws, size_t ws_size,
                              hipStream_t stream) {
  const float* imgs = (const float*)d_in[0];
  const float* caps = (const float*)d_in[1];
  const int* cap_lens = (const int*)d_in[3];   // img_lens (d_in[2]) unused by reference
  float* out = (float*)d_out;

  char* ws = (char*)d_ws;
  const size_t QBF_B = (size_t)NCAP * 32 * 4 * 512 * 2;      // 33,554,432
  const size_t IBF_B = (size_t)NIMG * 32 * 3 * 512 * 2;      // 25,165,824
  const size_t W1_B = (size_t)NCAP * WPAD * 4;               // 65,536
  const size_t GBF_B = (size_t)NIMG * 48 * 64 * 2;           // 1,572,864
  const size_t GD_B = (size_t)NIMG * 48 * 4;                 // 49,152
  unsigned short* qbfF = (unsigned short*)ws;
  unsigned short* ibfF = (unsigned short*)(ws + QBF_B);
  float* w1 = (float*)(ws + QBF_B + IBF_B);
  unsigned short* gbf = (unsigned short*)(ws + QBF_B + IBF_B + W1_B);
  float* gdiag = (float*)(ws + QBF_B + IBF_B + W1_B + GBF_B);
  int* perm = (int*)(ws + QBF_B + IBF_B + W1_B + GBF_B + GD_B);

  k_prep_w1<<<NCAP * WPAD, 256, 0, stream>>>(caps, cap_lens, w1);
  k_sort<<<1, NCAP, 0, stream>>>(cap_lens, perm);
  k_prep_caps_frag<<<dim3(32, NCAP), 256, 0, stream>>>(caps, cap_lens, qbfF);
  k_prep_imgs_frag<<<dim3(32, NIMG), 192, 0, stream>>>(imgs, ibfF);
  k_gram_mfma<<<NIMG, 64, 0, stream>>>(imgs, ibfF, gbf, gdiag);
  k_main<<<dim3(NIMG / 2, NCAP / 2), 256, 0, stream>>>(qbfF, ibfF, w1, gbf, gdiag, cap_lens, perm, out);
}